// Round 15
// baseline (143.825 us; speedup 1.0000x reference)
//
#include <hip/hip_runtime.h>
#include <hip/hip_bf16.h>
#include <stdint.h>

// MHA forward: B=2, L=2048, HID=1024, NH=16, HD=64. fp32 in/out, bf16 MFMA inside.
// R15: revert to R13 (best: qkv 41.3us, 0 bank conflicts, counted-vmcnt pipe3)
// + out_gemm split-K=2 (grid 256->512, 2 blocks/CU): partials atomicAdd'd into
// memset-zeroed d_out. Exactly 2 f32 contributions/element -> commutative ->
// bitwise deterministic. R14's tile-shrink falsified (MFMA density > occupancy).

#define L_SEQ 2048
#define HID 1024
#define NHEAD 16
#define HD 64

typedef __attribute__((ext_vector_type(8))) short bf16x8;
typedef __attribute__((ext_vector_type(8))) unsigned short u16x8;
typedef __attribute__((ext_vector_type(4))) float f32x4;

__device__ __forceinline__ unsigned short f2bf(float f) {
  unsigned int u = __builtin_bit_cast(unsigned int, f);
  u += 0x7fffu + ((u >> 16) & 1u);  // RNE; inputs are finite
  return (unsigned short)(u >> 16);
}

__device__ __forceinline__ unsigned int pk2bf(float a, float b) {
  unsigned int r;
  asm("v_cvt_pk_bf16_f32 %0, %1, %2" : "=v"(r) : "v"(a), "v"(b));
  return r;  // lo = bf16(a), hi = bf16(b)
}

__device__ __forceinline__ void gl_lds16(const void* g, void* l) {
  __builtin_amdgcn_global_load_lds(
      (const __attribute__((address_space(1))) unsigned int*)(uintptr_t)g,
      (__attribute__((address_space(3))) unsigned int*)(uint32_t)(uintptr_t)l,
      16, 0, 0);
}

__device__ __forceinline__ f32x4 mfma16(bf16x8 a, bf16x8 b, f32x4 c) {
  return __builtin_amdgcn_mfma_f32_16x16x32_bf16(a, b, c, 0, 0, 0);
}

// ---------------- fused converts (7 arrays) + lengths ----------------
__global__ __launch_bounds__(256)
void convert_all_kernel(const float* __restrict__ q, const float* __restrict__ k,
                        const float* __restrict__ v, const float* __restrict__ wq,
                        const float* __restrict__ wk, const float* __restrict__ wv,
                        const float* __restrict__ wo, const unsigned int* __restrict__ km,
                        unsigned short* __restrict__ qb, unsigned short* __restrict__ kb,
                        unsigned short* __restrict__ vb, unsigned short* __restrict__ wqb,
                        unsigned short* __restrict__ wkb, unsigned short* __restrict__ wvb,
                        unsigned short* __restrict__ wob, int* __restrict__ lens) {
  __shared__ int red[256];
  const int bid = blockIdx.x;
  const int t = threadIdx.x;
  if (bid == 8192) {
    unsigned int w0 = km[0];
    bool u8mode = (w0 != 1u);  // lengths >= 1024 so first 4 bools are all true
    for (int b = 0; b < 2; ++b) {
      int cnt = 0;
      if (u8mode) {
        const unsigned char* p = (const unsigned char*)km + b * L_SEQ;
        for (int i = t; i < L_SEQ; i += 256) cnt += (p[i] != 0) ? 1 : 0;
      } else {
        const unsigned int* p = km + b * L_SEQ;
        for (int i = t; i < L_SEQ; i += 256) cnt += (p[i] != 0) ? 1 : 0;
      }
      red[t] = cnt;
      __syncthreads();
      for (int s = 128; s > 0; s >>= 1) {
        if (t < s) red[t] += red[t + s];
        __syncthreads();
      }
      if (t == 0) lens[b] = red[0];
      __syncthreads();
    }
    return;
  }
  const float* src;
  unsigned short* dst;
  int base;
  if (bid < 6144) {
    int s = bid >> 11;
    base = (bid & 2047) * 2048;
    src = s == 0 ? q : (s == 1 ? k : v);
    dst = s == 0 ? qb : (s == 1 ? kb : vb);
  } else {
    int r = bid - 6144;
    int s = r >> 9;
    base = (r & 511) * 2048;
    src = s == 0 ? wq : (s == 1 ? wk : (s == 2 ? wv : wo));
    dst = s == 0 ? wqb : (s == 1 ? wkb : (s == 2 ? wvb : wob));
  }
  int i = base + t * 8;
  float4 a = *(const float4*)(src + i);
  float4 b4 = *(const float4*)(src + i + 4);
  u16x8 o;
  o[0] = f2bf(a.x); o[1] = f2bf(a.y); o[2] = f2bf(a.z); o[3] = f2bf(a.w);
  o[4] = f2bf(b4.x); o[5] = f2bf(b4.y); o[6] = f2bf(b4.z); o[7] = f2bf(b4.w);
  *(u16x8*)(dst + i) = o;
}

// ---------------- 128x128 GEMM core, 3-buffer counted-vmcnt pipeline,
// chunk-swizzled LDS (pos = chunk ^ ((row>>1)&3)). Kstride = row stride,
// nk = number of 32-wide K-steps (A/W pre-offset by caller for split-K). ----------------
__device__ __forceinline__ void gemm128_pipe3_core(const unsigned short* __restrict__ A,
                                                   const unsigned short* __restrict__ W,
                                                   int m0, int n0, int Kstride, int nk,
                                                   unsigned short* As, unsigned short* Bs,
                                                   f32x4 acc[4][4]) {
  const int tid = threadIdx.x;
  const int w = tid >> 6, lane = tid & 63;
  const int l15 = lane & 15, l4 = lane >> 4;
  const int wr = w >> 1, wc = w & 1;
#pragma unroll
  for (int i = 0; i < 4; ++i)
#pragma unroll
    for (int j = 0; j < 4; ++j) acc[i][j] = (f32x4){0.f, 0.f, 0.f, 0.f};

  // per-thread staging: LDS pos p at row r holds global k-chunk p ^ ((r>>1)&3)
  const int c0 = tid, c1 = 256 + tid;
  const int r0 = c0 >> 2, o0 = (((c0 & 3) ^ ((r0 >> 1) & 3))) * 8;
  const int r1 = c1 >> 2, o1 = (((c1 & 3) ^ ((r1 >> 1) & 3))) * 8;
  const unsigned short* A0 = A + (size_t)(m0 + r0) * Kstride + o0;
  const unsigned short* A1 = A + (size_t)(m0 + r1) * Kstride + o1;
  const unsigned short* W0 = W + (size_t)(n0 + r0) * Kstride + o0;
  const unsigned short* W1 = W + (size_t)(n0 + r1) * Kstride + o1;
  const int base0 = (w * 64) * 16;            // wave-uniform LDS dest bases
  const int base1 = (256 + w * 64) * 16;

  // fragment read offsets (elements), same XOR
  int aoff[4], boff[4];
#pragma unroll
  for (int i = 0; i < 4; ++i) {
    int Ra = wr * 64 + i * 16 + l15;
    aoff[i] = Ra * 32 + ((l4 ^ ((Ra >> 1) & 3)) * 8);
    int Rb = wc * 64 + i * 16 + l15;
    boff[i] = Rb * 32 + ((l4 ^ ((Rb >> 1) & 3)) * 8);
  }

  // prologue: stage tiles 0 and 1 into bufs 0 and 1 (8 loads outstanding)
  gl_lds16(A0, (char*)As + base0);
  gl_lds16(W0, (char*)Bs + base0);
  gl_lds16(A1, (char*)As + base1);
  gl_lds16(W1, (char*)Bs + base1);
  gl_lds16(A0 + 32, (char*)As + 8192 + base0);
  gl_lds16(W0 + 32, (char*)Bs + 8192 + base0);
  gl_lds16(A1 + 32, (char*)As + 8192 + base1);
  gl_lds16(W1 + 32, (char*)Bs + 8192 + base1);
  asm volatile("s_waitcnt vmcnt(4)" ::: "memory");  // tile 0 landed
  __builtin_amdgcn_s_barrier();
  asm volatile("" ::: "memory");

  int bc = 0;  // buffer holding tile t
  for (int t = 0; t < nk; ++t) {
    if (t + 2 < nk) {  // stage tile t+2 into buf (bc+2)%3
      int bs = bc + 2;
      if (bs >= 3) bs -= 3;
      const int kk = (t + 2) * 32;
      char* a = (char*)As + bs * 8192;
      char* b = (char*)Bs + bs * 8192;
      gl_lds16(A0 + kk, a + base0);
      gl_lds16(W0 + kk, b + base0);
      gl_lds16(A1 + kk, a + base1);
      gl_lds16(W1 + kk, b + base1);
    }
    const unsigned short* Asb = As + bc * 4096;
    const unsigned short* Bsb = Bs + bc * 4096;
    bf16x8 af[4], bfr[4];
#pragma unroll
    for (int i = 0; i < 4; ++i) af[i] = *(const bf16x8*)(Asb + aoff[i]);
#pragma unroll
    for (int j = 0; j < 4; ++j) bfr[j] = *(const bf16x8*)(Bsb + boff[j]);
    __builtin_amdgcn_s_setprio(1);
#pragma unroll
    for (int i = 0; i < 4; ++i)
#pragma unroll
      for (int j = 0; j < 4; ++j) acc[i][j] = mfma16(af[i], bfr[j], acc[i][j]);
    __builtin_amdgcn_s_setprio(0);
    if (t + 1 < nk) {
      if (t + 2 < nk)
        asm volatile("s_waitcnt vmcnt(4)" ::: "memory");  // tile t+1 landed
      else
        asm volatile("s_waitcnt vmcnt(0)" ::: "memory");  // last tile: full drain
      __builtin_amdgcn_s_barrier();
      asm volatile("" ::: "memory");
      ++bc;
      if (bc == 3) bc = 0;
    }
  }
}

// ---------------- fused QKV projection (bf16 A, pipe3 core, XCD swizzle) ----------------
__global__ __launch_bounds__(256)
void qkv_gemm_kernel(const unsigned short* __restrict__ qb, const unsigned short* __restrict__ kb,
                     const unsigned short* __restrict__ vb, const unsigned short* __restrict__ wq,
                     const unsigned short* __restrict__ wk, const unsigned short* __restrict__ wv,
                     const float* __restrict__ bq, const float* __restrict__ bk,
                     const float* __restrict__ bv, unsigned short* __restrict__ Qp,
                     unsigned short* __restrict__ Kp, unsigned short* __restrict__ Vtp) {
  __shared__ unsigned short As[3 * 128 * 32];
  __shared__ unsigned short Bs[3 * 128 * 32];
  const int id = blockIdx.x;
  const int g = (id & 7) * 96 + (id >> 3);
  const int mg = g >> 3;                 // 0..95 global m-tile (z-major)
  const int z = mg >> 5;
  const int m0 = (mg & 31) * 128;
  const int n0 = (g & 7) * 128;

  const unsigned short* A = z == 0 ? qb : (z == 1 ? kb : vb);
  const unsigned short* W = z == 0 ? wq : (z == 1 ? wk : wv);
  const float* bias = z == 0 ? bq : (z == 1 ? bk : bv);
  f32x4 acc[4][4];
  gemm128_pipe3_core(A, W, m0, n0, HID, HID >> 5, As, Bs, acc);

  const int tid = threadIdx.x;
  const int w = tid >> 6, lane = tid & 63;
  const int l15 = lane & 15, l4 = lane >> 4;
  const int wr = w >> 1, wc = w & 1;
  // Q gets 1/sqrt(64) * log2(e) folded in -> softmax runs in exp2 domain.
  const float scale = (z == 0) ? 0.125f * 1.44269504089f : 1.0f;
  if (z == 2) {
    // V^T: r=0..3 contiguous along ll -> one 8B packed store per (i,j)
#pragma unroll
    for (int i = 0; i < 4; ++i)
#pragma unroll
      for (int j = 0; j < 4; ++j) {
        int grow0 = m0 + wr * 64 + i * 16 + l4 * 4;
        int gcol = n0 + wc * 64 + j * 16 + l15;
        float bv_ = bias[gcol];
        int bb = grow0 >> 11, ll0 = grow0 & 2047;
        int hh = gcol >> 6, d = gcol & 63;
        uint2 pw;
        pw.x = pk2bf(acc[i][j][0] + bv_, acc[i][j][1] + bv_);
        pw.y = pk2bf(acc[i][j][2] + bv_, acc[i][j][3] + bv_);
        *(uint2*)(&Vtp[((size_t)(bb * NHEAD + hh) * HD + d) * L_SEQ + ll0]) = pw;
      }
  } else {
    unsigned short* P = (z == 0) ? Qp : Kp;
#pragma unroll
    for (int i = 0; i < 4; ++i)
#pragma unroll
      for (int j = 0; j < 4; ++j)
#pragma unroll
        for (int r = 0; r < 4; ++r) {
          int grow = m0 + wr * 64 + i * 16 + l4 * 4 + r;
          int gcol = n0 + wc * 64 + j * 16 + l15;
          float v = (acc[i][j][r] + bias[gcol]) * scale;
          int bb = grow >> 11, ll = grow & 2047;
          int hh = gcol >> 6, d = gcol & 63;
          P[((size_t)(bb * NHEAD + hh) * L_SEQ + ll) * HD + d] = f2bf(v);
        }
  }
}

// ---------------- output projection (pipe3 core, split-K=2, XCD swizzle) ----------------
// grid 512: g = (id&7)*64 + id>>3; n0 = (g&7)*128, kh = (g>>3)&1, m0 = (g>>4)*128.
// Each block computes a K-half partial and atomicAdds f32 into zeroed d_out.
// Exactly 2 contributions per element -> commutative -> deterministic.
__global__ __launch_bounds__(256)
void out_gemm_kernel(const unsigned short* __restrict__ att, const unsigned short* __restrict__ wo,
                     const float* __restrict__ bo, float* __restrict__ out) {
  __shared__ unsigned short As[3 * 128 * 32];
  __shared__ unsigned short Bs[3 * 128 * 32];
  const int id = blockIdx.x;
  const int g = (id & 7) * 64 + (id >> 3);
  const int n0 = (g & 7) * 128;
  const int kh = (g >> 3) & 1;
  const int m0 = (g >> 4) * 128;
  f32x4 acc[4][4];
  gemm128_pipe3_core(att + kh * 512, wo + kh * 512, m0, n0, HID, 16, As, Bs, acc);

  const int tid = threadIdx.x;
  const int w = tid >> 6, lane = tid & 63;
  const int l15 = lane & 15, l4 = lane >> 4;
  const int wr = w >> 1, wc = w & 1;
#pragma unroll
  for (int i = 0; i < 4; ++i)
#pragma unroll
    for (int j = 0; j < 4; ++j)
#pragma unroll
      for (int r = 0; r < 4; ++r) {
        int grow = m0 + wr * 64 + i * 16 + l4 * 4 + r;
        int gcol = n0 + wc * 64 + j * 16 + l15;
        float v = acc[i][j][r] + (kh == 0 ? bo[gcol] : 0.f);
        atomicAdd(&out[(size_t)grow * HID + gcol], v);
      }
}

// ---------------- flash attention (512 thr, paired subtiles, swapped softmax) ----------------
// flat grid 512; g = (id&7)*64 + id>>3: bh = g>>4 (same-bh blocks on one XCD), x = g&15.
__global__ __launch_bounds__(512)
void attn_kernel(const unsigned short* __restrict__ Qp, const unsigned short* __restrict__ Kp,
                 const unsigned short* __restrict__ Vtp, unsigned short* __restrict__ att,
                 const int* __restrict__ lens) {
  __shared__ unsigned short Ks[2][64 * 64];   // [buf][k][d], XOR-swizzled 16B chunks
  __shared__ unsigned short Vs[2][64 * 64];   // [buf][d][k], XOR-swizzled 16B chunks
  __shared__ unsigned short Ps[8][16 * 72];   // wave-private P [q][k], padded stride 72

  const int id = blockIdx.x;
  const int g = (id & 7) * 64 + (id >> 3);
  const int bh = g >> 4;
  const int x = g & 15;
  const int b = bh >> 4, h = bh & 15;
  const int tid = threadIdx.x, w = tid >> 6, lane = tid & 63;
  const int l15 = lane & 15, l4 = lane >> 4;
  const int len = lens[b];
  const int sub = (w < 4) ? x : (31 - x);
  const int qw0 = sub * 64 + (w & 3) * 16;

  const unsigned short* Qg = Qp + (size_t)bh * L_SEQ * HD;
  const unsigned short* Kg = Kp + (size_t)bh * L_SEQ * HD;
  const unsigned short* Vg = Vtp + (size_t)bh * HD * L_SEQ;

  const int rr = tid >> 3, cb = tid & 7;
  const int swz = (cb ^ (rr & 7)) * 8;
  const unsigned short* KgRow = Kg + (size_t)rr * HD + swz;       // + k0*HD
  const unsigned short* VgRow = Vg + (size_t)rr * L_SEQ + swz;    // + k0

  bf16x8 qf[2];
#pragma unroll
  for (int kk = 0; kk < 2; ++kk)
    qf[kk] = *(const bf16x8*)(Qg + (size_t)(qw0 + l15) * HD + kk * 32 + l4 * 8);

  f32x4 acc[4];
#pragma unroll
  for (int n = 0; n < 4; ++n) acc[n] = (f32x4){0.f, 0.f, 0.f, 0.f};
  float mq = -1e30f, lq = 0.f;

  int koff[4][2];
#pragma unroll
  for (int n = 0; n < 4; ++n)
#pragma unroll
    for (int kk = 0; kk < 2; ++kk) {
      int row = n * 16 + l15;
      koff[n][kk] = row * 128 + (((l4 + kk * 4) ^ (row & 7)) * 16);
    }

  const int len_r = ((len + 63) >> 6) << 6;
  const int hi_end = 64 * (32 - x);
  const int kv_end = (hi_end < len_r) ? hi_end : len_r;
  const int nt = kv_end >> 6;

  gl_lds16(KgRow, (char*)&Ks[0][0] + w * 1024);
  gl_lds16(VgRow, (char*)&Vs[0][0] + w * 1024);
  __syncthreads();

  int cur = 0;
  for (int t = 0; t < nt; ++t) {
    const int k0 = t * 64;
    if (t + 1 < nt) {
      const int k1 = k0 + 64;
      gl_lds16(KgRow + (size_t)k1 * HD, (char*)&Ks[cur ^ 1][0] + w * 1024);
      gl_lds16(VgRow + k1, (char*)&Vs[cur ^ 1][0] + w * 1024);
    }
    if (k0 <= qw0 + 15) {
      const char* Kb = (const char*)&Ks[cur][0];
      const char* Vb = (const char*)&Vs[cur][0];
      f32x4 s[4];
#pragma unroll
      for (int n = 0; n < 4; ++n) s[n] = (f32x4){0.f, 0.f, 0.f, 0.f};
      __builtin_amdgcn_s_setprio(1);
#pragma unroll
      for (int kk = 0; kk < 2; ++kk) {
#pragma unroll
        for (int n = 0; n < 4; ++n)
          s[n] = mfma16(*(const bf16x8*)(Kb + koff[n][kk]), qf[kk], s[n]);
      }
      __builtin_amdgcn_s_setprio(0);
      if (!(k0 + 63 <= qw0 && k0 + 64 <= len)) {
        const int qa = qw0 + l15;
#pragma unroll
        for (int n = 0; n < 4; ++n)
#pragma unroll
          for (int r = 0; r < 4; ++r) {
            int ka = k0 + n * 16 + l4 * 4 + r;
            if (ka > qa || ka >= len) s[n][r] = -1e30f;
          }
      }
      float v01 = fmaxf(fmaxf(s[0][0], s[0][1]), fmaxf(s[0][2], s[0][3]));
      float v23 = fmaxf(fmaxf(s[1][0], s[1][1]), fmaxf(s[1][2], s[1][3]));
      float v45 = fmaxf(fmaxf(s[2][0], s[2][1]), fmaxf(s[2][2], s[2][3]));
      float v67 = fmaxf(fmaxf(s[3][0], s[3][1]), fmaxf(s[3][2], s[3][3]));
      float v = fmaxf(fmaxf(v01, v23), fmaxf(v45, v67));
      v = fmaxf(v, __shfl_xor(v, 16));
      v = fmaxf(v, __shfl_xor(v, 32));
      if (!__all(v - mq <= 8.0f)) {  // defer-max (T13), exp2 domain
        float mnew = fmaxf(mq, v);
        float alpha = __builtin_amdgcn_exp2f(mq - mnew);
        mq = mnew;
        float ar[4];
#pragma unroll
        for (int r = 0; r < 4; ++r) ar[r] = __shfl(alpha, l4 * 4 + r, 64);
#pragma unroll
        for (int n = 0; n < 4; ++n)
#pragma unroll
          for (int r = 0; r < 4; ++r) acc[n][r] *= ar[r];
        lq *= alpha;
      }
      float rs = 0.f;
#pragma unroll
      for (int n = 0; n < 4; ++n)
#pragma unroll
        for (int r = 0; r < 4; ++r) {
          float p = __builtin_amdgcn_exp2f(s[n][r] - mq);
          s[n][r] = p;
          rs += p;
        }
      rs += __shfl_xor(rs, 16);
      rs += __shfl_xor(rs, 32);
      lq += rs;
#pragma unroll
      for (int n = 0; n < 4; ++n) {
        uint2 pw;
        pw.x = pk2bf(s[n][0], s[n][1]);
        pw.y = pk2bf(s[n][2], s[n][3]);
        *(uint2*)(&Ps[w][l15 * 72 + n * 16 + l4 * 4]) = pw;
      }
      bf16x8 pf[2];
#pragma unroll
      for (int kk = 0; kk < 2; ++kk)
        pf[kk] = *(const bf16x8*)(&Ps[w][l15 * 72 + kk * 32 + l4 * 8]);
      __builtin_amdgcn_s_setprio(1);
#pragma unroll
      for (int kk = 0; kk < 2; ++kk) {
#pragma unroll
        for (int n = 0; n < 4; ++n)
          acc[n] = mfma16(pf[kk], *(const bf16x8*)(Vb + koff[n][kk]), acc[n]);
      }
      __builtin_amdgcn_s_setprio(0);
    }
    __syncthreads();
    cur ^= 1;
  }

  float invq = 1.0f / lq;
  float invr[4];
#pragma unroll
  for (int r = 0; r < 4; ++r) invr[r] = __shfl(invq, l4 * 4 + r, 64);
#pragma unroll
  for (int r = 0; r < 4; ++r) {
    int qa = qw0 + l4 * 4 + r;
#pragma unroll
    for (int n = 0; n < 4; ++n)
      att[((size_t)(b * L_SEQ + qa)) * HID + h * HD + n * 16 + l15] = f2bf(acc[n][r] * invr[r]);
  }
}

extern "C" void kernel_launch(void* const* d_in, const int* in_sizes, int n_in,
                              void* d_out, int out_size, void* d_ws, size_t ws_size,
                              hipStream_t stream) {
  const float* query = (const float*)d_in[0];
  const float* key = (const float*)d_in[1];
  const float* value = (const float*)d_in[2];
  const unsigned int* key_mask = (const unsigned int*)d_in[3];
  // d_in[4] = attn_mask (static causal triu) -- computed in-kernel, unused
  const float* Wq = (const float*)d_in[5];
  const float* bq = (const float*)d_in[6];
  const float* Wk = (const float*)d_in[7];
  const float* bk = (const float*)d_in[8];
  const float* Wv = (const float*)d_in[9];
  const float* bv = (const float*)d_in[10];
  const float* Wo = (const float*)d_in[11];
  const float* bo = (const float*)d_in[12];

  char* ws = (char*)d_ws;
  const size_t SZ_X = (size_t)4096 * 1024 * 2;  // 8 MiB
  const size_t SZ_W = (size_t)1024 * 1024 * 2;  // 2 MiB
  unsigned short* qb = (unsigned short*)(ws);
  unsigned short* kb = (unsigned short*)(ws + SZ_X);
  unsigned short* vb = (unsigned short*)(ws + 2 * SZ_X);
  unsigned short* wqb = (unsigned short*)(ws + 3 * SZ_X);
  unsigned short* wkb = (unsigned short*)(ws + 3 * SZ_X + SZ_W);
  unsigned short* wvb = (unsigned short*)(ws + 3 * SZ_X + 2 * SZ_W);
  unsigned short* wob = (unsigned short*)(ws + 3 * SZ_X + 3 * SZ_W);
  unsigned short* Qp = (unsigned short*)(ws + 3 * SZ_X + 4 * SZ_W);
  unsigned short* Kp = (unsigned short*)(ws + 4 * SZ_X + 4 * SZ_W);
  unsigned short* Vtp = (unsigned short*)(ws + 5 * SZ_X + 4 * SZ_W);
  unsigned short* att = (unsigned short*)(ws + 6 * SZ_X + 4 * SZ_W);
  int* lens = (int*)(ws + 7 * SZ_X + 4 * SZ_W);

  convert_all_kernel<<<8193, 256, 0, stream>>>(query, key, value, Wq, Wk, Wv, Wo, key_mask,
                                               qb, kb, vb, wqb, wkb, wvb, wob, lens);
  qkv_gemm_kernel<<<768, 256, 0, stream>>>(qb, kb, vb, wqb, wkb, wvb, bq, bk, bv,
                                           Qp, Kp, Vtp);
  attn_kernel<<<512, 512, 0, stream>>>(Qp, Kp, Vtp, att, lens);
  hipMemsetAsync(d_out, 0, (size_t)out_size * sizeof(float), stream);
  out_gemm_kernel<<<512, 256, 0, stream>>>(att, wob, bo, (float*)d_out);
}

// Round 16
// 117.673 us; speedup vs baseline: 1.2222x; 1.2222x over previous
//
#include <hip/hip_runtime.h>
#include <hip/hip_bf16.h>
#include <stdint.h>

// MHA forward: B=2, L=2048, HID=1024, NH=16, HD=64. fp32 in/out, bf16 MFMA inside.
// R16: exact revert to R13 (best measured: 118.1us). R15's split-K+memset
// falsified (fill dispatch cost 41us under graph replay). Composition:
// convert_all + qkv (128^2 pipe3 counted-vmcnt, chunk-swizzled LDS, 0 bank
// conflicts, XCD n-fastest swizzle) + attn (512-thr paired subtiles, swapped
// softmax, defer-max, XCD swizzle) + out_gemm (pipe3, XCD swizzle).

#define L_SEQ 2048
#define HID 1024
#define NHEAD 16
#define HD 64

typedef __attribute__((ext_vector_type(8))) short bf16x8;
typedef __attribute__((ext_vector_type(8))) unsigned short u16x8;
typedef __attribute__((ext_vector_type(4))) float f32x4;

__device__ __forceinline__ unsigned short f2bf(float f) {
  unsigned int u = __builtin_bit_cast(unsigned int, f);
  u += 0x7fffu + ((u >> 16) & 1u);  // RNE; inputs are finite
  return (unsigned short)(u >> 16);
}

__device__ __forceinline__ unsigned int pk2bf(float a, float b) {
  unsigned int r;
  asm("v_cvt_pk_bf16_f32 %0, %1, %2" : "=v"(r) : "v"(a), "v"(b));
  return r;  // lo = bf16(a), hi = bf16(b)
}

__device__ __forceinline__ void gl_lds16(const void* g, void* l) {
  __builtin_amdgcn_global_load_lds(
      (const __attribute__((address_space(1))) unsigned int*)(uintptr_t)g,
      (__attribute__((address_space(3))) unsigned int*)(uint32_t)(uintptr_t)l,
      16, 0, 0);
}

__device__ __forceinline__ f32x4 mfma16(bf16x8 a, bf16x8 b, f32x4 c) {
  return __builtin_amdgcn_mfma_f32_16x16x32_bf16(a, b, c, 0, 0, 0);
}

// ---------------- fused converts (7 arrays) + lengths ----------------
__global__ __launch_bounds__(256)
void convert_all_kernel(const float* __restrict__ q, const float* __restrict__ k,
                        const float* __restrict__ v, const float* __restrict__ wq,
                        const float* __restrict__ wk, const float* __restrict__ wv,
                        const float* __restrict__ wo, const unsigned int* __restrict__ km,
                        unsigned short* __restrict__ qb, unsigned short* __restrict__ kb,
                        unsigned short* __restrict__ vb, unsigned short* __restrict__ wqb,
                        unsigned short* __restrict__ wkb, unsigned short* __restrict__ wvb,
                        unsigned short* __restrict__ wob, int* __restrict__ lens) {
  __shared__ int red[256];
  const int bid = blockIdx.x;
  const int t = threadIdx.x;
  if (bid == 8192) {
    unsigned int w0 = km[0];
    bool u8mode = (w0 != 1u);  // lengths >= 1024 so first 4 bools are all true
    for (int b = 0; b < 2; ++b) {
      int cnt = 0;
      if (u8mode) {
        const unsigned char* p = (const unsigned char*)km + b * L_SEQ;
        for (int i = t; i < L_SEQ; i += 256) cnt += (p[i] != 0) ? 1 : 0;
      } else {
        const unsigned int* p = km + b * L_SEQ;
        for (int i = t; i < L_SEQ; i += 256) cnt += (p[i] != 0) ? 1 : 0;
      }
      red[t] = cnt;
      __syncthreads();
      for (int s = 128; s > 0; s >>= 1) {
        if (t < s) red[t] += red[t + s];
        __syncthreads();
      }
      if (t == 0) lens[b] = red[0];
      __syncthreads();
    }
    return;
  }
  const float* src;
  unsigned short* dst;
  int base;
  if (bid < 6144) {
    int s = bid >> 11;
    base = (bid & 2047) * 2048;
    src = s == 0 ? q : (s == 1 ? k : v);
    dst = s == 0 ? qb : (s == 1 ? kb : vb);
  } else {
    int r = bid - 6144;
    int s = r >> 9;
    base = (r & 511) * 2048;
    src = s == 0 ? wq : (s == 1 ? wk : (s == 2 ? wv : wo));
    dst = s == 0 ? wqb : (s == 1 ? wkb : (s == 2 ? wvb : wob));
  }
  int i = base + t * 8;
  float4 a = *(const float4*)(src + i);
  float4 b4 = *(const float4*)(src + i + 4);
  u16x8 o;
  o[0] = f2bf(a.x); o[1] = f2bf(a.y); o[2] = f2bf(a.z); o[3] = f2bf(a.w);
  o[4] = f2bf(b4.x); o[5] = f2bf(b4.y); o[6] = f2bf(b4.z); o[7] = f2bf(b4.w);
  *(u16x8*)(dst + i) = o;
}

// ---------------- 128x128 GEMM core, 3-buffer counted-vmcnt pipeline,
// chunk-swizzled LDS (pos = chunk ^ ((row>>1)&3)) ----------------
__device__ __forceinline__ void gemm128_pipe3_core(const unsigned short* __restrict__ A,
                                                   const unsigned short* __restrict__ W,
                                                   int m0, int n0, int K,
                                                   unsigned short* As, unsigned short* Bs,
                                                   f32x4 acc[4][4]) {
  const int tid = threadIdx.x;
  const int w = tid >> 6, lane = tid & 63;
  const int l15 = lane & 15, l4 = lane >> 4;
  const int wr = w >> 1, wc = w & 1;
#pragma unroll
  for (int i = 0; i < 4; ++i)
#pragma unroll
    for (int j = 0; j < 4; ++j) acc[i][j] = (f32x4){0.f, 0.f, 0.f, 0.f};

  const int nk = K >> 5;
  // per-thread staging: LDS pos p at row r holds global k-chunk p ^ ((r>>1)&3)
  const int c0 = tid, c1 = 256 + tid;
  const int r0 = c0 >> 2, o0 = (((c0 & 3) ^ ((r0 >> 1) & 3))) * 8;
  const int r1 = c1 >> 2, o1 = (((c1 & 3) ^ ((r1 >> 1) & 3))) * 8;
  const unsigned short* A0 = A + (size_t)(m0 + r0) * K + o0;
  const unsigned short* A1 = A + (size_t)(m0 + r1) * K + o1;
  const unsigned short* W0 = W + (size_t)(n0 + r0) * K + o0;
  const unsigned short* W1 = W + (size_t)(n0 + r1) * K + o1;
  const int base0 = (w * 64) * 16;            // wave-uniform LDS dest bases
  const int base1 = (256 + w * 64) * 16;

  // fragment read offsets (elements), same XOR
  int aoff[4], boff[4];
#pragma unroll
  for (int i = 0; i < 4; ++i) {
    int Ra = wr * 64 + i * 16 + l15;
    aoff[i] = Ra * 32 + ((l4 ^ ((Ra >> 1) & 3)) * 8);
    int Rb = wc * 64 + i * 16 + l15;
    boff[i] = Rb * 32 + ((l4 ^ ((Rb >> 1) & 3)) * 8);
  }

  // prologue: stage tiles 0 and 1 into bufs 0 and 1 (8 loads outstanding)
  gl_lds16(A0, (char*)As + base0);
  gl_lds16(W0, (char*)Bs + base0);
  gl_lds16(A1, (char*)As + base1);
  gl_lds16(W1, (char*)Bs + base1);
  gl_lds16(A0 + 32, (char*)As + 8192 + base0);
  gl_lds16(W0 + 32, (char*)Bs + 8192 + base0);
  gl_lds16(A1 + 32, (char*)As + 8192 + base1);
  gl_lds16(W1 + 32, (char*)Bs + 8192 + base1);
  asm volatile("s_waitcnt vmcnt(4)" ::: "memory");  // tile 0 landed
  __builtin_amdgcn_s_barrier();
  asm volatile("" ::: "memory");

  int bc = 0;  // buffer holding tile t
  for (int t = 0; t < nk; ++t) {
    if (t + 2 < nk) {  // stage tile t+2 into buf (bc+2)%3
      int bs = bc + 2;
      if (bs >= 3) bs -= 3;
      const int kk = (t + 2) * 32;
      char* a = (char*)As + bs * 8192;
      char* b = (char*)Bs + bs * 8192;
      gl_lds16(A0 + kk, a + base0);
      gl_lds16(W0 + kk, b + base0);
      gl_lds16(A1 + kk, a + base1);
      gl_lds16(W1 + kk, b + base1);
    }
    const unsigned short* Asb = As + bc * 4096;
    const unsigned short* Bsb = Bs + bc * 4096;
    bf16x8 af[4], bfr[4];
#pragma unroll
    for (int i = 0; i < 4; ++i) af[i] = *(const bf16x8*)(Asb + aoff[i]);
#pragma unroll
    for (int j = 0; j < 4; ++j) bfr[j] = *(const bf16x8*)(Bsb + boff[j]);
    __builtin_amdgcn_s_setprio(1);
#pragma unroll
    for (int i = 0; i < 4; ++i)
#pragma unroll
      for (int j = 0; j < 4; ++j) acc[i][j] = mfma16(af[i], bfr[j], acc[i][j]);
    __builtin_amdgcn_s_setprio(0);
    if (t + 1 < nk) {
      if (t + 2 < nk)
        asm volatile("s_waitcnt vmcnt(4)" ::: "memory");  // tile t+1 landed
      else
        asm volatile("s_waitcnt vmcnt(0)" ::: "memory");  // last tile: full drain
      __builtin_amdgcn_s_barrier();
      asm volatile("" ::: "memory");
      ++bc;
      if (bc == 3) bc = 0;
    }
  }
}

// ---------------- fused QKV projection (bf16 A, pipe3 core, XCD swizzle) ----------------
__global__ __launch_bounds__(256)
void qkv_gemm_kernel(const unsigned short* __restrict__ qb, const unsigned short* __restrict__ kb,
                     const unsigned short* __restrict__ vb, const unsigned short* __restrict__ wq,
                     const unsigned short* __restrict__ wk, const unsigned short* __restrict__ wv,
                     const float* __restrict__ bq, const float* __restrict__ bk,
                     const float* __restrict__ bv, unsigned short* __restrict__ Qp,
                     unsigned short* __restrict__ Kp, unsigned short* __restrict__ Vtp) {
  __shared__ unsigned short As[3 * 128 * 32];
  __shared__ unsigned short Bs[3 * 128 * 32];
  const int id = blockIdx.x;
  const int g = (id & 7) * 96 + (id >> 3);
  const int mg = g >> 3;                 // 0..95 global m-tile (z-major)
  const int z = mg >> 5;
  const int m0 = (mg & 31) * 128;
  const int n0 = (g & 7) * 128;

  const unsigned short* A = z == 0 ? qb : (z == 1 ? kb : vb);
  const unsigned short* W = z == 0 ? wq : (z == 1 ? wk : wv);
  const float* bias = z == 0 ? bq : (z == 1 ? bk : bv);
  f32x4 acc[4][4];
  gemm128_pipe3_core(A, W, m0, n0, HID, As, Bs, acc);

  const int tid = threadIdx.x;
  const int w = tid >> 6, lane = tid & 63;
  const int l15 = lane & 15, l4 = lane >> 4;
  const int wr = w >> 1, wc = w & 1;
  // Q gets 1/sqrt(64) * log2(e) folded in -> softmax runs in exp2 domain.
  const float scale = (z == 0) ? 0.125f * 1.44269504089f : 1.0f;
  if (z == 2) {
    // V^T: r=0..3 contiguous along ll -> one 8B packed store per (i,j)
#pragma unroll
    for (int i = 0; i < 4; ++i)
#pragma unroll
      for (int j = 0; j < 4; ++j) {
        int grow0 = m0 + wr * 64 + i * 16 + l4 * 4;
        int gcol = n0 + wc * 64 + j * 16 + l15;
        float bv_ = bias[gcol];
        int bb = grow0 >> 11, ll0 = grow0 & 2047;
        int hh = gcol >> 6, d = gcol & 63;
        uint2 pw;
        pw.x = pk2bf(acc[i][j][0] + bv_, acc[i][j][1] + bv_);
        pw.y = pk2bf(acc[i][j][2] + bv_, acc[i][j][3] + bv_);
        *(uint2*)(&Vtp[((size_t)(bb * NHEAD + hh) * HD + d) * L_SEQ + ll0]) = pw;
      }
  } else {
    unsigned short* P = (z == 0) ? Qp : Kp;
#pragma unroll
    for (int i = 0; i < 4; ++i)
#pragma unroll
      for (int j = 0; j < 4; ++j)
#pragma unroll
        for (int r = 0; r < 4; ++r) {
          int grow = m0 + wr * 64 + i * 16 + l4 * 4 + r;
          int gcol = n0 + wc * 64 + j * 16 + l15;
          float v = (acc[i][j][r] + bias[gcol]) * scale;
          int bb = grow >> 11, ll = grow & 2047;
          int hh = gcol >> 6, d = gcol & 63;
          P[((size_t)(bb * NHEAD + hh) * L_SEQ + ll) * HD + d] = f2bf(v);
        }
  }
}

// ---------------- output projection (pipe3 core, XCD swizzle) ----------------
__global__ __launch_bounds__(256)
void out_gemm_kernel(const unsigned short* __restrict__ att, const unsigned short* __restrict__ wo,
                     const float* __restrict__ bo, float* __restrict__ out) {
  __shared__ unsigned short As[3 * 128 * 32];
  __shared__ unsigned short Bs[3 * 128 * 32];
  const int id = blockIdx.x;
  const int swz = (id & 7) * 32 + (id >> 3);
  const int m0 = (swz >> 3) * 128, n0 = (swz & 7) * 128;
  f32x4 acc[4][4];
  gemm128_pipe3_core(att, wo, m0, n0, HID, As, Bs, acc);

  const int tid = threadIdx.x;
  const int w = tid >> 6, lane = tid & 63;
  const int l15 = lane & 15, l4 = lane >> 4;
  const int wr = w >> 1, wc = w & 1;
#pragma unroll
  for (int i = 0; i < 4; ++i)
#pragma unroll
    for (int j = 0; j < 4; ++j)
#pragma unroll
      for (int r = 0; r < 4; ++r) {
        int grow = m0 + wr * 64 + i * 16 + l4 * 4 + r;
        int gcol = n0 + wc * 64 + j * 16 + l15;
        out[(size_t)grow * HID + gcol] = acc[i][j][r] + bo[gcol];
      }
}

// ---------------- flash attention (512 thr, paired subtiles, swapped softmax) ----------------
// flat grid 512; g = (id&7)*64 + id>>3: bh = g>>4 (same-bh blocks on one XCD), x = g&15.
__global__ __launch_bounds__(512)
void attn_kernel(const unsigned short* __restrict__ Qp, const unsigned short* __restrict__ Kp,
                 const unsigned short* __restrict__ Vtp, unsigned short* __restrict__ att,
                 const int* __restrict__ lens) {
  __shared__ unsigned short Ks[2][64 * 64];   // [buf][k][d], XOR-swizzled 16B chunks
  __shared__ unsigned short Vs[2][64 * 64];   // [buf][d][k], XOR-swizzled 16B chunks
  __shared__ unsigned short Ps[8][16 * 72];   // wave-private P [q][k], padded stride 72

  const int id = blockIdx.x;
  const int g = (id & 7) * 64 + (id >> 3);
  const int bh = g >> 4;
  const int x = g & 15;
  const int b = bh >> 4, h = bh & 15;
  const int tid = threadIdx.x, w = tid >> 6, lane = tid & 63;
  const int l15 = lane & 15, l4 = lane >> 4;
  const int len = lens[b];
  const int sub = (w < 4) ? x : (31 - x);
  const int qw0 = sub * 64 + (w & 3) * 16;

  const unsigned short* Qg = Qp + (size_t)bh * L_SEQ * HD;
  const unsigned short* Kg = Kp + (size_t)bh * L_SEQ * HD;
  const unsigned short* Vg = Vtp + (size_t)bh * HD * L_SEQ;

  const int rr = tid >> 3, cb = tid & 7;
  const int swz = (cb ^ (rr & 7)) * 8;
  const unsigned short* KgRow = Kg + (size_t)rr * HD + swz;       // + k0*HD
  const unsigned short* VgRow = Vg + (size_t)rr * L_SEQ + swz;    // + k0

  bf16x8 qf[2];
#pragma unroll
  for (int kk = 0; kk < 2; ++kk)
    qf[kk] = *(const bf16x8*)(Qg + (size_t)(qw0 + l15) * HD + kk * 32 + l4 * 8);

  f32x4 acc[4];
#pragma unroll
  for (int n = 0; n < 4; ++n) acc[n] = (f32x4){0.f, 0.f, 0.f, 0.f};
  float mq = -1e30f, lq = 0.f;

  int koff[4][2];
#pragma unroll
  for (int n = 0; n < 4; ++n)
#pragma unroll
    for (int kk = 0; kk < 2; ++kk) {
      int row = n * 16 + l15;
      koff[n][kk] = row * 128 + (((l4 + kk * 4) ^ (row & 7)) * 16);
    }

  const int len_r = ((len + 63) >> 6) << 6;
  const int hi_end = 64 * (32 - x);
  const int kv_end = (hi_end < len_r) ? hi_end : len_r;
  const int nt = kv_end >> 6;

  gl_lds16(KgRow, (char*)&Ks[0][0] + w * 1024);
  gl_lds16(VgRow, (char*)&Vs[0][0] + w * 1024);
  __syncthreads();

  int cur = 0;
  for (int t = 0; t < nt; ++t) {
    const int k0 = t * 64;
    if (t + 1 < nt) {
      const int k1 = k0 + 64;
      gl_lds16(KgRow + (size_t)k1 * HD, (char*)&Ks[cur ^ 1][0] + w * 1024);
      gl_lds16(VgRow + k1, (char*)&Vs[cur ^ 1][0] + w * 1024);
    }
    if (k0 <= qw0 + 15) {
      const char* Kb = (const char*)&Ks[cur][0];
      const char* Vb = (const char*)&Vs[cur][0];
      f32x4 s[4];
#pragma unroll
      for (int n = 0; n < 4; ++n) s[n] = (f32x4){0.f, 0.f, 0.f, 0.f};
      __builtin_amdgcn_s_setprio(1);
#pragma unroll
      for (int kk = 0; kk < 2; ++kk) {
#pragma unroll
        for (int n = 0; n < 4; ++n)
          s[n] = mfma16(*(const bf16x8*)(Kb + koff[n][kk]), qf[kk], s[n]);
      }
      __builtin_amdgcn_s_setprio(0);
      if (!(k0 + 63 <= qw0 && k0 + 64 <= len)) {
        const int qa = qw0 + l15;
#pragma unroll
        for (int n = 0; n < 4; ++n)
#pragma unroll
          for (int r = 0; r < 4; ++r) {
            int ka = k0 + n * 16 + l4 * 4 + r;
            if (ka > qa || ka >= len) s[n][r] = -1e30f;
          }
      }
      float v01 = fmaxf(fmaxf(s[0][0], s[0][1]), fmaxf(s[0][2], s[0][3]));
      float v23 = fmaxf(fmaxf(s[1][0], s[1][1]), fmaxf(s[1][2], s[1][3]));
      float v45 = fmaxf(fmaxf(s[2][0], s[2][1]), fmaxf(s[2][2], s[2][3]));
      float v67 = fmaxf(fmaxf(s[3][0], s[3][1]), fmaxf(s[3][2], s[3][3]));
      float v = fmaxf(fmaxf(v01, v23), fmaxf(v45, v67));
      v = fmaxf(v, __shfl_xor(v, 16));
      v = fmaxf(v, __shfl_xor(v, 32));
      if (!__all(v - mq <= 8.0f)) {  // defer-max (T13), exp2 domain
        float mnew = fmaxf(mq, v);
        float alpha = __builtin_amdgcn_exp2f(mq - mnew);
        mq = mnew;
        float ar[4];
#pragma unroll
        for (int r = 0; r < 4; ++r) ar[r] = __shfl(alpha, l4 * 4 + r, 64);
#pragma unroll
        for (int n = 0; n < 4; ++n)
#pragma unroll
          for (int r = 0; r < 4; ++r) acc[n][r] *= ar[r];
        lq *= alpha;
      }
      float rs = 0.f;
#pragma unroll
      for (int n = 0; n < 4; ++n)
#pragma unroll
        for (int r = 0; r < 4; ++r) {
          float p = __builtin_amdgcn_exp2f(s[n][r] - mq);
          s[n][r] = p;
          rs += p;
        }
      rs += __shfl_xor(rs, 16);
      rs += __shfl_xor(rs, 32);
      lq += rs;
#pragma unroll
      for (int n = 0; n < 4; ++n) {
        uint2 pw;
        pw.x = pk2bf(s[n][0], s[n][1]);
        pw.y = pk2bf(s[n][2], s[n][3]);
        *(uint2*)(&Ps[w][l15 * 72 + n * 16 + l4 * 4]) = pw;
      }
      bf16x8 pf[2];
#pragma unroll
      for (int kk = 0; kk < 2; ++kk)
        pf[kk] = *(const bf16x8*)(&Ps[w][l15 * 72 + kk * 32 + l4 * 8]);
      __builtin_amdgcn_s_setprio(1);
#pragma unroll
      for (int kk = 0; kk < 2; ++kk) {
#pragma unroll
        for (int n = 0; n < 4; ++n)
          acc[n] = mfma16(pf[kk], *(const bf16x8*)(Vb + koff[n][kk]), acc[n]);
      }
      __builtin_amdgcn_s_setprio(0);
    }
    __syncthreads();
    cur ^= 1;
  }

  float invq = 1.0f / lq;
  float invr[4];
#pragma unroll
  for (int r = 0; r < 4; ++r) invr[r] = __shfl(invq, l4 * 4 + r, 64);
#pragma unroll
  for (int r = 0; r < 4; ++r) {
    int qa = qw0 + l4 * 4 + r;
#pragma unroll
    for (int n = 0; n < 4; ++n)
      att[((size_t)(b * L_SEQ + qa)) * HID + h * HD + n * 16 + l15] = f2bf(acc[n][r] * invr[r]);
  }
}

extern "C" void kernel_launch(void* const* d_in, const int* in_sizes, int n_in,
                              void* d_out, int out_size, void* d_ws, size_t ws_size,
                              hipStream_t stream) {
  const float* query = (const float*)d_in[0];
  const float* key = (const float*)d_in[1];
  const float* value = (const float*)d_in[2];
  const unsigned int* key_mask = (const unsigned int*)d_in[3];
  // d_in[4] = attn_mask (static causal triu) -- computed in-kernel, unused
  const float* Wq = (const float*)d_in[5];
  const float* bq = (const float*)d_in[6];
  const float* Wk = (const float*)d_in[7];
  const float* bk = (const float*)d_in[8];
  const float* Wv = (const float*)d_in[9];
  const float* bv = (const float*)d_in[10];
  const float* Wo = (const float*)d_in[11];
  const float* bo = (const float*)d_in[12];

  char* ws = (char*)d_ws;
  const size_t SZ_X = (size_t)4096 * 1024 * 2;  // 8 MiB
  const size_t SZ_W = (size_t)1024 * 1024 * 2;  // 2 MiB
  unsigned short* qb = (unsigned short*)(ws);
  unsigned short* kb = (unsigned short*)(ws + SZ_X);
  unsigned short* vb = (unsigned short*)(ws + 2 * SZ_X);
  unsigned short* wqb = (unsigned short*)(ws + 3 * SZ_X);
  unsigned short* wkb = (unsigned short*)(ws + 3 * SZ_X + SZ_W);
  unsigned short* wvb = (unsigned short*)(ws + 3 * SZ_X + 2 * SZ_W);
  unsigned short* wob = (unsigned short*)(ws + 3 * SZ_X + 3 * SZ_W);
  unsigned short* Qp = (unsigned short*)(ws + 3 * SZ_X + 4 * SZ_W);
  unsigned short* Kp = (unsigned short*)(ws + 4 * SZ_X + 4 * SZ_W);
  unsigned short* Vtp = (unsigned short*)(ws + 5 * SZ_X + 4 * SZ_W);
  unsigned short* att = (unsigned short*)(ws + 6 * SZ_X + 4 * SZ_W);
  int* lens = (int*)(ws + 7 * SZ_X + 4 * SZ_W);

  convert_all_kernel<<<8193, 256, 0, stream>>>(query, key, value, Wq, Wk, Wv, Wo, key_mask,
                                               qb, kb, vb, wqb, wkb, wvb, wob, lens);
  qkv_gemm_kernel<<<768, 256, 0, stream>>>(qb, kb, vb, wqb, wkb, wvb, bq, bk, bv,
                                           Qp, Kp, Vtp);
  attn_kernel<<<512, 512, 0, stream>>>(Qp, Kp, Vtp, att, lens);
  out_gemm_kernel<<<256, 256, 0, stream>>>(att, wob, bo, (float*)d_out);
}